// Round 4
// baseline (72.519 us; speedup 1.0000x reference)
//
#include <hip/hip_runtime.h>
#include <math.h>

typedef float f32x2  __attribute__((ext_vector_type(2)));
typedef float f32x16 __attribute__((ext_vector_type(16)));

// constant-address-space pointee => uniform loads lower to s_load_dwordx16 (SMEM)
typedef __attribute__((address_space(4))) const f32x16 cvec16_t;

__device__ __forceinline__ float decode_scalar(const int* p) {
    int i = *p;
    if (i > -16777216 && i < 16777216) return (float)i;
    return __int_as_float(i);
}

// d = q_bcast * ref_pair + acc   (packed fp32, ref pair comes from SGPRs)
__device__ __forceinline__ f32x2 pk_fma_qlo(f32x2 q, f32x2 rs, f32x2 acc) {
    f32x2 d;  // both result lanes use q.lo
    asm("v_pk_fma_f32 %0, %1, %2, %3 op_sel:[0,0,0] op_sel_hi:[0,1,1]"
        : "=v"(d) : "v"(q), "s"(rs), "v"(acc));
    return d;
}
__device__ __forceinline__ f32x2 pk_fma_qhi(f32x2 q, f32x2 rs, f32x2 acc) {
    f32x2 d;  // both result lanes use q.hi
    asm("v_pk_fma_f32 %0, %1, %2, %3 op_sel:[1,0,0] op_sel_hi:[1,1,1]"
        : "=v"(d) : "v"(q), "s"(rs), "v"(acc));
    return d;
}
__device__ __forceinline__ float min3f(float a, float b, float c) {
    float d;
    asm("v_min3_f32 %0, %1, %2, %3" : "=v"(d) : "v"(a), "v"(b), "v"(c));
    return d;
}

// Prep: pair-SoA layout, 32B per pair of points: {x0,x1,y0,y1,z0,z1,rn0,rn1}.
// Pad points (beyond n, up to n16) get rn=+INF so they never win the min.
__global__ __launch_bounds__(256) void pack_pairs(
    const float* __restrict__ preds, const float* __restrict__ gts,
    int nP, int nG, int nP16, int nG16, int B, float4* __restrict__ dst)
{
    const int pairsP = B * (nP16 >> 1);
    const int pairsG = B * (nG16 >> 1);
    const int t = blockIdx.x * 256 + threadIdx.x;
    if (t >= pairsP + pairsG) return;
    const float* src; int n, n16, pi; float4* out;
    if (t < pairsP) { src = preds; n = nP; n16 = nP16; pi = t; out = dst; }
    else { src = gts; n = nG; n16 = nG16; pi = t - pairsP; out = dst + (size_t)pairsP * 2; }
    const int perB = n16 >> 1;
    const int b = pi / perB, k = pi - b * perB;
    const int i0 = 2 * k, i1 = 2 * k + 1;
    float x0=0,y0=0,z0=0,rn0=INFINITY, x1=0,y1=0,z1=0,rn1=INFINITY;
    if (i0 < n) { const float* s = src + ((size_t)b*n + i0)*3; x0=s[0]; y0=s[1]; z0=s[2]; rn0 = x0*x0+y0*y0+z0*z0; }
    if (i1 < n) { const float* s = src + ((size_t)b*n + i1)*3; x1=s[0]; y1=s[1]; z1=s[2]; rn1 = x1*x1+y1*y1+z1*z1; }
    out[(size_t)pi*2]     = make_float4(x0, x1, y0, y1);
    out[(size_t)pi*2 + 1] = make_float4(z0, z1, rn0, rn1);
}

// Stage 1: refs streamed through SGPRs (s_load_dwordx16, double-buffered, no LDS,
// no barriers). 8 queries/lane packed 2-per-VGPR-pair; op_sel broadcasts query,
// v_pk_fma consumes the SGPR ref pair directly. ~2.13 VALU instr per pair.
__global__ __launch_bounds__(256) void nn_partial_min(
    const float* __restrict__ preds, const float* __restrict__ gts,
    const float* __restrict__ packed,
    int M, int N, int nP16, int nG16, int B, int rsplit, int Qmax,
    float* __restrict__ part)
{
    const int zc    = blockIdx.z;
    const int dir   = zc / rsplit;          // 0: q=preds ref=gts ; 1: q=gts ref=preds
    const int chunk = zc - dir * rsplit;
    const int b     = blockIdx.y;

    const int Q = dir ? N : M;
    const float* __restrict__ qsrc = (dir ? gts : preds) + (size_t)b * Q * 3;

    const int pairsP = B * (nP16 >> 1);
    const int refN16 = dir ? nP16 : nG16;
    const size_t pairBase = dir ? ((size_t)b * (nP16 >> 1))
                                : ((size_t)pairsP + (size_t)b * (nG16 >> 1));

    const int groups = refN16 >> 3;                   // 8-point groups (2 x 64B)
    const int gPer   = (groups + rsplit - 1) / rsplit;
    const int g0     = chunk * gPer;
    const int g1     = min(groups, g0 + gPer);

    const int tid = threadIdx.x;
    const int Qk  = (Q + 7) >> 3;
    const int j0  = blockIdx.x * 256 + tid;

    f32x2 qx[4], qy[4], qz[4];
    float qn[8], best[8];
    #pragma unroll
    for (int k = 0; k < 8; ++k) {
        const int jk = j0 + k * Qk;
        float x=0, y=0, z=0, w=0;
        if (jk < Q) { const float* s = qsrc + (size_t)jk*3; x=s[0]; y=s[1]; z=s[2]; w = x*x+y*y+z*z; }
        const int p = k >> 1;
        if ((k & 1) == 0) { qx[p].x = -2.f*x; qy[p].x = -2.f*y; qz[p].x = -2.f*z; }
        else              { qx[p].y = -2.f*x; qy[p].y = -2.f*y; qz[p].y = -2.f*z; }
        qn[k] = w; best[k] = INFINITY;
    }

    const cvec16_t* gp = (const cvec16_t*)(packed + pairBase * 8);

    if (g0 < g1) {
        f32x16 c0 = gp[2*g0], c1 = gp[2*g0 + 1];
        for (int g = g0; g < g1; ++g) {
            const int gn = (g + 1 < g1) ? g + 1 : g;
            const f32x16 n0 = gp[2*gn], n1 = gp[2*gn + 1];
            #pragma unroll
            for (int h = 0; h < 4; ++h) {
                const f32x16 v = (h < 2) ? c0 : c1;
                const int o = (h & 1) * 8;
                const f32x2 xs = { v[o+0], v[o+1] };
                const f32x2 ys = { v[o+2], v[o+3] };
                const f32x2 zs = { v[o+4], v[o+5] };
                const f32x2 rn = { v[o+6], v[o+7] };   // copied to VGPR pair once, shared by 8 chains
                #pragma unroll
                for (int p = 0; p < 4; ++p) {
                    const f32x2 dlo = pk_fma_qlo(qx[p], xs, pk_fma_qlo(qy[p], ys, pk_fma_qlo(qz[p], zs, rn)));
                    const f32x2 dhi = pk_fma_qhi(qx[p], xs, pk_fma_qhi(qy[p], ys, pk_fma_qhi(qz[p], zs, rn)));
                    best[2*p]     = min3f(dlo.x, dlo.y, best[2*p]);
                    best[2*p + 1] = min3f(dhi.x, dhi.y, best[2*p + 1]);
                }
            }
            c0 = n0; c1 = n1;
        }
    }

    const size_t base = (((size_t)dir * B + b) * rsplit + chunk) * (size_t)Qmax;
    #pragma unroll
    for (int k = 0; k < 8; ++k) {
        const int jk = j0 + k * Qk;
        if (jk < Q) part[base + jk] = best[k] + qn[k];
    }
}

// Stage 2: combine rsplit partial mins, Huber, wave reduce, atomicAdd.
__global__ __launch_bounds__(256) void huber_reduce(
    const float* __restrict__ part, const int* __restrict__ cptr,
    int M, int N, int B, int rsplit, int Qmax, float* __restrict__ out)
{
    const int dir = blockIdx.z;
    const int b   = blockIdx.y;
    const int Q   = dir ? N : M;
    const int j   = blockIdx.x * blockDim.x + threadIdx.x;

    float h = 0.f;
    if (j < Q) {
        const size_t base = (((size_t)dir * B + b) * rsplit) * (size_t)Qmax + j;
        float v = part[base];
        #pragma unroll 8
        for (int k = 1; k < rsplit; ++k) v = fminf(v, part[base + (size_t)k * Qmax]);
        const float c = decode_scalar(cptr);
        h = (v < c) ? (0.5f * v * v) : (c * v - 0.5f * c * c);
    }

    #pragma unroll
    for (int off = 32; off > 0; off >>= 1) h += __shfl_down(h, off, 64);
    if ((threadIdx.x & 63) == 0) atomicAdd(out, h);
}

extern "C" void kernel_launch(void* const* d_in, const int* in_sizes, int n_in,
                              void* d_out, int out_size, void* d_ws, size_t ws_size,
                              hipStream_t stream) {
    const float* preds = (const float*)d_in[0];
    const float* gts   = (const float*)d_in[1];
    const int*   cptr  = (const int*)d_in[2];

    const int B = 4, D = 3;
    const int M = in_sizes[0] / (B * D);
    const int N = in_sizes[1] / (B * D);
    const int Qmax = (M > N) ? M : N;
    const int nP16 = (M + 15) & ~15;   // per-batch padded (keeps 64B alignment of groups)
    const int nG16 = (N + 15) & ~15;

    const size_t packedBytes = ((size_t)B * nP16 + (size_t)B * nG16) * 16; // 16B/point
    int rsplit = 32;
    while (rsplit > 1 &&
           packedBytes + 2ull * B * rsplit * (size_t)Qmax * sizeof(float) > ws_size)
        rsplit >>= 1;

    float* packed = (float*)d_ws;
    float* part   = (float*)((char*)d_ws + packedBytes);
    float* out    = (float*)d_out;

    hipMemsetAsync(d_out, 0, (size_t)out_size * sizeof(float), stream);

    const int totalPairs = B * (nP16 >> 1) + B * (nG16 >> 1);
    pack_pairs<<<dim3((totalPairs + 255) / 256), 256, 0, stream>>>(
        preds, gts, M, N, nP16, nG16, B, (float4*)packed);

    const int Qk = (Qmax + 7) >> 3;
    dim3 g1((Qk + 255) / 256, B, 2 * rsplit);
    nn_partial_min<<<g1, 256, 0, stream>>>(preds, gts, packed, M, N, nP16, nG16, B,
                                           rsplit, Qmax, part);

    dim3 g2((Qmax + 255) / 256, B, 2);
    huber_reduce<<<g2, 256, 0, stream>>>(part, cptr, M, N, B, rsplit, Qmax, out);
}

// Round 5
// 71.038 us; speedup vs baseline: 1.0209x; 1.0209x over previous
//
#include <hip/hip_runtime.h>
#include <math.h>

typedef _Float16 f16x8 __attribute__((ext_vector_type(8)));
typedef float f32x4 __attribute__((ext_vector_type(4)));

#define TILE_R 1024  // refs staged per block: 1024 * 32B = 32 KB LDS

__device__ __forceinline__ float decode_scalar(const int* p) {
    int i = *p;
    if (i > -16777216 && i < 16777216) return (float)i;
    return __int_as_float(i);
}
__device__ __forceinline__ float min3f(float a, float b, float c) {
    float d;
    asm("v_min3_f32 %0, %1, %2, %3" : "=v"(d) : "v"(a), "v"(b), "v"(c));
    return d;
}

// Pack each point into two 16-f16 encodings (a = -2*pt, split hi+lo; rn = |pt|^2):
//  A (as query): k0-2 ah, k3-5 al, k6-8 ah, k9-11 al, k12 rnh, k13 rnl, k14 1, k15 1
//  B (as ref)  : k0-2 bh, k3-5 bh, k6-8 bl, k9-11 bl, k12 1, k13 1, k14 rnh, k15 rnl
// => sum_k A_k*B_k = (ah+al).(bh+bl) + qn + rn = ||q-r||^2 exactly to ~fp32.
__global__ __launch_bounds__(256) void pack_pts(
    const float* __restrict__ preds, const float* __restrict__ gts,
    int M, int N, int M16, int N16, int B,
    f16x8* __restrict__ Ap, f16x8* __restrict__ Ag,
    f16x8* __restrict__ Bp, f16x8* __restrict__ Bg)
{
    const int which = blockIdx.y;
    const int n   = which ? N : M;
    const int n16 = which ? N16 : M16;
    f16x8* A  = which ? Ag : Ap;
    f16x8* Bo = which ? Bg : Bp;
    const float* src = which ? gts : preds;
    const int idx = blockIdx.x * 256 + threadIdx.x;
    if (idx >= B * n16) return;
    const int b = idx / n16, i = idx - b * n16;
    f16x8 alo, ahi, blo, bhi;
    const _Float16 z0 = (_Float16)0.f, one = (_Float16)1.f;
    if (i < n) {
        const float* s = src + ((size_t)b * n + i) * 3;
        const float x = s[0], y = s[1], z = s[2];
        const float rn = fmaf(x, x, fmaf(y, y, z * z));
        const float ax = -2.f * x, ay = -2.f * y, az = -2.f * z;
        const _Float16 ahx = (_Float16)ax, ahy = (_Float16)ay, ahz = (_Float16)az;
        const _Float16 alx = (_Float16)(ax - (float)ahx);
        const _Float16 aly = (_Float16)(ay - (float)ahy);
        const _Float16 alz = (_Float16)(az - (float)ahz);
        const _Float16 bhx = (_Float16)x, bhy = (_Float16)y, bhz = (_Float16)z;
        const _Float16 blx = (_Float16)(x - (float)bhx);
        const _Float16 bly = (_Float16)(y - (float)bhy);
        const _Float16 blz = (_Float16)(z - (float)bhz);
        const _Float16 rh = (_Float16)rn;
        const _Float16 rl = (_Float16)(rn - (float)rh);
        alo = (f16x8){ahx, ahy, ahz, alx, aly, alz, ahx, ahy};
        ahi = (f16x8){ahz, alx, aly, alz, rh, rl, one, one};
        blo = (f16x8){bhx, bhy, bhz, bhx, bhy, bhz, blx, bly};
        bhi = (f16x8){blz, blx, bly, blz, one, one, rh, rl};
    } else {
        const _Float16 inf16 = (_Float16)__builtin_huge_valf();
        alo = (f16x8){z0, z0, z0, z0, z0, z0, z0, z0};
        ahi = (f16x8){z0, z0, z0, z0, z0, z0, one, one};
        blo = (f16x8){z0, z0, z0, z0, z0, z0, z0, z0};
        bhi = (f16x8){z0, z0, z0, z0, one, one, inf16, z0};  // pad ref -> dist = +inf
    }
    A[(size_t)idx * 2]      = alo;
    A[(size_t)idx * 2 + 1]  = ahi;
    Bo[(size_t)idx * 2]     = blo;
    Bo[(size_t)idx * 2 + 1] = bhi;
}

// Fused: per (dir, batch, 128-query block): sweep ALL refs via MFMA 16x16 tiles,
// per-row running min (min3, tile-paired), then Huber + reduce + atomicAdd.
__global__ __launch_bounds__(256) void chamfer_fused(
    const f16x8* __restrict__ Ap, const f16x8* __restrict__ Ag,
    const f16x8* __restrict__ Bp, const f16x8* __restrict__ Bg,
    int M, int N, int M16, int N16,
    const int* __restrict__ cptr, float* __restrict__ out)
{
    const int dir = blockIdx.z;        // 0: q=preds ref=gts ; 1: q=gts ref=preds
    const int b   = blockIdx.y;
    const int Q   = dir ? N : M;
    const int Rp  = dir ? M16 : N16;
    const f16x8* __restrict__ A  = dir ? (Ag + (size_t)b * N16 * 2) : (Ap + (size_t)b * M16 * 2);
    const f16x8* __restrict__ Bb = dir ? (Bp + (size_t)b * M16 * 2) : (Bg + (size_t)b * N16 * 2);

    const int q0blk = blockIdx.x * 128;
    if (q0blk >= Q) return;
    const int tid  = threadIdx.x;
    const int lane = tid & 63, w = tid >> 6;
    const int q0   = q0blk + w * 32;      // this wave: queries q0..q0+31 (2 frags)
    const int lrow = lane & 15, lk = lane >> 4;

    const f16x8 zf = (f16x8){(_Float16)0.f, (_Float16)0.f, (_Float16)0.f, (_Float16)0.f,
                             (_Float16)0.f, (_Float16)0.f, (_Float16)0.f, (_Float16)0.f};
    f16x8 af0 = zf, af1 = zf;
    if (lane < 32) {
        const int qa = q0 + lrow, qb = q0 + 16 + lrow;
        if (qa < Q) af0 = A[(size_t)qa * 2 + lk];
        if (qb < Q) af1 = A[(size_t)qb * 2 + lk];
    }

    __shared__ f16x8 sB[TILE_R * 2 + 2];  // +2: zero units for lanes 32-63
    __shared__ float wsum[4];
    if (tid == 0) { sB[TILE_R * 2] = zf; sB[TILE_R * 2 + 1] = zf; }

    const f32x4 z4 = {0.f, 0.f, 0.f, 0.f};
    f32x4 rm0 = {INFINITY, INFINITY, INFINITY, INFINITY};
    f32x4 rm1 = {INFINITY, INFINITY, INFINITY, INFINITY};

    const int zidx = TILE_R * 2;          // LDS broadcast-zero for upper half-wave
    const int lbase = lrow * 2 + lk;      // per-lane offset within a tile

    for (int s0 = 0; s0 < Rp; s0 += TILE_R) {
        const int st = min(TILE_R, Rp - s0);
        __syncthreads();
        for (int u = tid; u < st * 2; u += 256) sB[u] = Bb[(size_t)s0 * 2 + u];
        __syncthreads();
        const int nt = st >> 4;
        #pragma unroll 2
        for (int t = 0; t + 2 <= nt; t += 2) {
            const int i0 = (lane < 32) ? (t * 32 + lbase) : zidx;
            const int i1 = (lane < 32) ? ((t + 1) * 32 + lbase) : zidx;
            const f16x8 bf0 = sB[i0];
            const f16x8 bf1 = sB[i1];
            const f32x4 aA0 = __builtin_amdgcn_mfma_f32_16x16x32_f16(af0, bf0, z4, 0, 0, 0);
            const f32x4 aA1 = __builtin_amdgcn_mfma_f32_16x16x32_f16(af1, bf0, z4, 0, 0, 0);
            const f32x4 aB0 = __builtin_amdgcn_mfma_f32_16x16x32_f16(af0, bf1, z4, 0, 0, 0);
            const f32x4 aB1 = __builtin_amdgcn_mfma_f32_16x16x32_f16(af1, bf1, z4, 0, 0, 0);
            #pragma unroll
            for (int j = 0; j < 4; ++j) {
                rm0[j] = min3f(aA0[j], aB0[j], rm0[j]);
                rm1[j] = min3f(aA1[j], aB1[j], rm1[j]);
            }
        }
        if (nt & 1) {
            const int t = nt - 1;
            const int i0 = (lane < 32) ? (t * 32 + lbase) : zidx;
            const f16x8 bf0 = sB[i0];
            const f32x4 aA0 = __builtin_amdgcn_mfma_f32_16x16x32_f16(af0, bf0, z4, 0, 0, 0);
            const f32x4 aA1 = __builtin_amdgcn_mfma_f32_16x16x32_f16(af1, bf0, z4, 0, 0, 0);
            #pragma unroll
            for (int j = 0; j < 4; ++j) {
                rm0[j] = fminf(rm0[j], aA0[j]);
                rm1[j] = fminf(rm1[j], aA1[j]);
            }
        }
    }

    // reduce row-mins across the 16 lanes holding different ref-columns
    #pragma unroll
    for (int m2 = 1; m2 <= 8; m2 <<= 1) {
        #pragma unroll
        for (int j = 0; j < 4; ++j) {
            rm0[j] = fminf(rm0[j], __shfl_xor(rm0[j], m2, 64));
            rm1[j] = fminf(rm1[j], __shfl_xor(rm1[j], m2, 64));
        }
    }

    float hs = 0.f;
    if ((lane & 15) == 0) {
        const float c = decode_scalar(cptr);
        const float mh = -0.5f * c * c;
        const int rbase = (lane >> 4) * 4;  // D row = 4*(lane>>4)+j
        #pragma unroll
        for (int j = 0; j < 4; ++j) {
            const int qa = q0 + rbase + j;
            if (qa < Q) { const float v = rm0[j]; hs += (v < c) ? 0.5f * v * v : fmaf(c, v, mh); }
            const int qb = q0 + 16 + rbase + j;
            if (qb < Q) { const float v = rm1[j]; hs += (v < c) ? 0.5f * v * v : fmaf(c, v, mh); }
        }
    }
    hs += __shfl_xor(hs, 16, 64);
    hs += __shfl_xor(hs, 32, 64);
    if (lane == 0) wsum[w] = hs;
    __syncthreads();
    if (tid == 0) atomicAdd(out, wsum[0] + wsum[1] + wsum[2] + wsum[3]);
}

extern "C" void kernel_launch(void* const* d_in, const int* in_sizes, int n_in,
                              void* d_out, int out_size, void* d_ws, size_t ws_size,
                              hipStream_t stream) {
    const float* preds = (const float*)d_in[0];
    const float* gts   = (const float*)d_in[1];
    const int*   cptr  = (const int*)d_in[2];

    const int B = 4, D = 3;
    const int M = in_sizes[0] / (B * D);
    const int N = in_sizes[1] / (B * D);
    const int M16 = (M + 15) & ~15;
    const int N16 = (N + 15) & ~15;
    const int Qmax = (M > N) ? M : N;

    // ws layout: Ap | Ag | Bp | Bg   (each point = 2 x f16x8 = 32 B)
    f16x8* Ap = (f16x8*)d_ws;
    f16x8* Ag = Ap + (size_t)B * M16 * 2;
    f16x8* Bp = Ag + (size_t)B * N16 * 2;
    f16x8* Bg = Bp + (size_t)B * M16 * 2;

    hipMemsetAsync(d_out, 0, (size_t)out_size * sizeof(float), stream);

    const int n16max = (M16 > N16) ? M16 : N16;
    dim3 g0((B * n16max + 255) / 256, 2, 1);
    pack_pts<<<g0, 256, 0, stream>>>(preds, gts, M, N, M16, N16, B, Ap, Ag, Bp, Bg);

    dim3 g1((Qmax + 127) / 128, B, 2);
    chamfer_fused<<<g1, 256, 0, stream>>>(Ap, Ag, Bp, Bg, M, N, M16, N16, cptr,
                                          (float*)d_out);
}

// Round 6
// 62.617 us; speedup vs baseline: 1.1581x; 1.1345x over previous
//
#include <hip/hip_runtime.h>
#include <math.h>

typedef _Float16 f16x8 __attribute__((ext_vector_type(8)));
typedef float f32x16 __attribute__((ext_vector_type(16)));

#define TILE 512   // refs per LDS stage: 512 * 32B = 16 KB

__device__ __forceinline__ float decode_scalar(const int* p) {
    int i = *p;
    if (i > -16777216 && i < 16777216) return (float)i;
    return __int_as_float(i);
}
__device__ __forceinline__ float min3f(float a, float b, float c) {
    float d;
    asm("v_min3_f32 %0, %1, %2, %3" : "=v"(d) : "v"(a), "v"(b), "v"(c));
    return d;
}

// Encoding (K=16), a = -2*pt, hi/lo f16 split, rn = |pt|^2:
//  A (query): [ah3, al3, ah3, al3, qnh, qnl, 1, 1]
//  B (ref)  : [bh3, bh3, bl3, bl3, 1, 1, rnh, rnl]
//  sum_k A_k B_k = (ah+al)·(bh+bl) + qn + rn = ||q-r||^2 (exact to ~fp32)
__global__ __launch_bounds__(256) void pack_pts(
    const float* __restrict__ preds, const float* __restrict__ gts,
    int M, int N, int Mp, int Np, int B,
    f16x8* __restrict__ Ap, f16x8* __restrict__ Ag,
    f16x8* __restrict__ Bp, f16x8* __restrict__ Bg)
{
    const int which = blockIdx.y;
    const int n  = which ? N : M;
    const int np = which ? Np : Mp;
    f16x8* A  = which ? Ag : Ap;
    f16x8* Bo = which ? Bg : Bp;
    const float* src = which ? gts : preds;
    const int idx = blockIdx.x * 256 + threadIdx.x;
    if (idx >= B * np) return;
    const int b = idx / np, i = idx - b * np;
    f16x8 a0, a1, b0, b1;
    const _Float16 z0 = (_Float16)0.f, one = (_Float16)1.f;
    if (i < n) {
        const float* s = src + ((size_t)b * n + i) * 3;
        const float x = s[0], y = s[1], z = s[2];
        const float rn = fmaf(x, x, fmaf(y, y, z * z));
        const float ax = -2.f * x, ay = -2.f * y, az = -2.f * z;
        const _Float16 ahx = (_Float16)ax, ahy = (_Float16)ay, ahz = (_Float16)az;
        const _Float16 alx = (_Float16)(ax - (float)ahx);
        const _Float16 aly = (_Float16)(ay - (float)ahy);
        const _Float16 alz = (_Float16)(az - (float)ahz);
        const _Float16 bhx = (_Float16)x, bhy = (_Float16)y, bhz = (_Float16)z;
        const _Float16 blx = (_Float16)(x - (float)bhx);
        const _Float16 bly = (_Float16)(y - (float)bhy);
        const _Float16 blz = (_Float16)(z - (float)bhz);
        const _Float16 rh = (_Float16)rn;
        const _Float16 rl = (_Float16)(rn - (float)rh);
        a0 = (f16x8){ahx, ahy, ahz, alx, aly, alz, ahx, ahy};
        a1 = (f16x8){ahz, alx, aly, alz, rh, rl, one, one};
        b0 = (f16x8){bhx, bhy, bhz, bhx, bhy, bhz, blx, bly};
        b1 = (f16x8){blz, blx, bly, blz, one, one, rh, rl};
    } else {
        const _Float16 inf16 = (_Float16)__builtin_huge_valf();
        a0 = (f16x8){z0, z0, z0, z0, z0, z0, z0, z0};
        a1 = (f16x8){z0, z0, z0, z0, z0, z0, one, one};
        b0 = (f16x8){z0, z0, z0, z0, z0, z0, z0, z0};
        b1 = (f16x8){z0, z0, z0, z0, one, one, inf16, z0};  // pad ref -> +inf dist
    }
    A[(size_t)idx * 2]      = a0;
    A[(size_t)idx * 2 + 1]  = a1;
    Bo[(size_t)idx * 2]     = b0;
    Bo[(size_t)idx * 2 + 1] = b1;
}

// Stage 1: 32x32x16 MFMA distance tiles, running column-min per query row.
// Per wave: 64 queries (2 A-frags). Per 32-ref sub-tile: 1 ds_read_b128/lane.
__global__ __launch_bounds__(256) void nn_mfma(
    const f16x8* __restrict__ Ap, const f16x8* __restrict__ Ag,
    const f16x8* __restrict__ Bp, const f16x8* __restrict__ Bg,
    int Mp, int Np, int B, int rsplit, int Qmaxp, float* __restrict__ part)
{
    const int zc    = blockIdx.z;
    const int dir   = zc / rsplit;       // 0: q=preds ref=gts ; 1: q=gts ref=preds
    const int chunk = zc - dir * rsplit;
    const int b     = blockIdx.y;

    const int Qp = dir ? Np : Mp;
    const int Rp = dir ? Mp : Np;
    const f16x8* __restrict__ A  = dir ? (Ag + (size_t)b * Np * 2) : (Ap + (size_t)b * Mp * 2);
    const f16x8* __restrict__ Bb = dir ? (Bp + (size_t)b * Mp * 2) : (Bg + (size_t)b * Np * 2);

    const int q0blk = blockIdx.x * 256;
    if (q0blk >= Qp) return;
    const int tid  = threadIdx.x;
    const int lane = tid & 63, w = tid >> 6;
    const int q0   = q0blk + w * 64;            // wave handles queries q0..q0+63
    const int lrow = lane & 31, lh = lane >> 5; // A row / k-half

    const f16x8 af0 = A[(size_t)(q0 + lrow) * 2 + lh];
    const f16x8 af1 = A[(size_t)(q0 + 32 + lrow) * 2 + lh];

    __shared__ f16x8 sB[TILE * 2];

    const f32x16 z16 = {0.f,0.f,0.f,0.f, 0.f,0.f,0.f,0.f, 0.f,0.f,0.f,0.f, 0.f,0.f,0.f,0.f};
    f32x16 rm0, rm1;
    #pragma unroll
    for (int j = 0; j < 16; ++j) { rm0[j] = INFINITY; rm1[j] = INFINITY; }

    const int chunkSpan = ((Rp / TILE + rsplit - 1) / rsplit) * TILE;
    const int c0 = chunk * chunkSpan;
    const int c1 = min(Rp, c0 + chunkSpan);

    for (int s0 = c0; s0 < c1; s0 += TILE) {
        __syncthreads();
        #pragma unroll
        for (int k = 0; k < 4; ++k)
            sB[tid + k * 256] = Bb[(size_t)s0 * 2 + tid + k * 256];
        __syncthreads();

        const char* sbase = (const char*)sB + lrow * 32 + lh * 16;
        #pragma unroll
        for (int tp = 0; tp < 8; ++tp) {
            const f16x8 bf0 = *(const f16x8*)(sbase + (2 * tp) * 1024);
            const f16x8 bf1 = *(const f16x8*)(sbase + (2 * tp + 1) * 1024);
            const f32x16 d00 = __builtin_amdgcn_mfma_f32_32x32x16_f16(af0, bf0, z16, 0, 0, 0);
            const f32x16 d01 = __builtin_amdgcn_mfma_f32_32x32x16_f16(af0, bf1, z16, 0, 0, 0);
            #pragma unroll
            for (int j = 0; j < 16; ++j) rm0[j] = min3f(d00[j], d01[j], rm0[j]);
            const f32x16 d10 = __builtin_amdgcn_mfma_f32_32x32x16_f16(af1, bf0, z16, 0, 0, 0);
            const f32x16 d11 = __builtin_amdgcn_mfma_f32_32x32x16_f16(af1, bf1, z16, 0, 0, 0);
            #pragma unroll
            for (int j = 0; j < 16; ++j) rm1[j] = min3f(d10[j], d11[j], rm1[j]);
        }
    }

    // reduce over the 32 ref-columns (lanes with same k-half hold different cols)
    #pragma unroll
    for (int m2 = 1; m2 <= 16; m2 <<= 1) {
        #pragma unroll
        for (int j = 0; j < 16; ++j) {
            rm0[j] = fminf(rm0[j], __shfl_xor(rm0[j], m2, 64));
            rm1[j] = fminf(rm1[j], __shfl_xor(rm1[j], m2, 64));
        }
    }

    // lanes 0 and 32 hold complementary row sets: row = (j&3)+8*(j>>2)+4*lh
    if ((lane & 31) == 0) {
        const size_t pbase = (((size_t)dir * B + b) * rsplit + chunk) * (size_t)Qmaxp + q0;
        #pragma unroll
        for (int j = 0; j < 16; ++j) {
            const int row = (j & 3) + 8 * (j >> 2) + 4 * lh;
            part[pbase + row]      = rm0[j];
            part[pbase + 32 + row] = rm1[j];
        }
    }
}

// Stage 2: combine rsplit partial mins, Huber, wave reduce, atomicAdd.
__global__ __launch_bounds__(256) void huber_reduce(
    const float* __restrict__ part, const int* __restrict__ cptr,
    int M, int N, int B, int rsplit, int Qmaxp, float* __restrict__ out)
{
    const int dir = blockIdx.z;
    const int b   = blockIdx.y;
    const int Q   = dir ? N : M;
    const int j   = blockIdx.x * blockDim.x + threadIdx.x;

    float h = 0.f;
    if (j < Q) {
        const size_t base = (((size_t)dir * B + b) * rsplit) * (size_t)Qmaxp + j;
        float v = part[base];
        #pragma unroll 4
        for (int k = 1; k < rsplit; ++k) v = fminf(v, part[base + (size_t)k * Qmaxp]);
        const float c = decode_scalar(cptr);
        h = (v < c) ? (0.5f * v * v) : fmaf(c, v, -0.5f * c * c);
    }

    #pragma unroll
    for (int off = 32; off > 0; off >>= 1) h += __shfl_down(h, off, 64);
    if ((threadIdx.x & 63) == 0) atomicAdd(out, h);
}

extern "C" void kernel_launch(void* const* d_in, const int* in_sizes, int n_in,
                              void* d_out, int out_size, void* d_ws, size_t ws_size,
                              hipStream_t stream) {
    const float* preds = (const float*)d_in[0];
    const float* gts   = (const float*)d_in[1];
    const int*   cptr  = (const int*)d_in[2];

    const int B = 4, D = 3;
    const int M = in_sizes[0] / (B * D);
    const int N = in_sizes[1] / (B * D);
    const int Mp = (M + TILE - 1) & ~(TILE - 1);   // pad to TILE multiple
    const int Np = (N + TILE - 1) & ~(TILE - 1);
    const int Qmaxp = (Mp > Np) ? Mp : Np;
    const int rsplit = 4;

    // ws: Ap | Ag | Bp | Bg | part   (each point = 2 x f16x8 = 32 B)
    f16x8* Ap = (f16x8*)d_ws;
    f16x8* Ag = Ap + (size_t)B * Mp * 2;
    f16x8* Bp = Ag + (size_t)B * Np * 2;
    f16x8* Bg = Bp + (size_t)B * Mp * 2;
    float* part = (float*)(Bg + (size_t)B * Np * 2);

    hipMemsetAsync(d_out, 0, (size_t)out_size * sizeof(float), stream);

    const int npmax = (Mp > Np) ? Mp : Np;
    dim3 g0((B * npmax + 255) / 256, 2, 1);
    pack_pts<<<g0, 256, 0, stream>>>(preds, gts, M, N, Mp, Np, B, Ap, Ag, Bp, Bg);

    dim3 g1(Qmaxp / 256, B, 2 * rsplit);
    nn_mfma<<<g1, 256, 0, stream>>>(Ap, Ag, Bp, Bg, Mp, Np, B, rsplit, Qmaxp, part);

    dim3 g2(((M > N ? M : N) + 255) / 256, B, 2);
    huber_reduce<<<g2, 256, 0, stream>>>(part, cptr, M, N, B, rsplit, Qmaxp,
                                         (float*)d_out);
}

// Round 7
// 58.700 us; speedup vs baseline: 1.2354x; 1.0667x over previous
//
#include <hip/hip_runtime.h>
#include <math.h>

typedef _Float16 f16x8 __attribute__((ext_vector_type(8)));
typedef float f32x16 __attribute__((ext_vector_type(16)));

#define TILE 512   // refs per LDS stage: 512 * 32B = 16 KB

__device__ __forceinline__ float decode_scalar(const int* p) {
    int i = *p;
    if (i > -16777216 && i < 16777216) return (float)i;
    return __int_as_float(i);
}
__device__ __forceinline__ float min3f(float a, float b, float c) {
    float d;
    asm("v_min3_f32 %0, %1, %2, %3" : "=v"(d) : "v"(a), "v"(b), "v"(c));
    return d;
}

// K=16 encoding, a = -2*pt, hi/lo f16 split, rn = |pt|^2:
//  A (query): [ah3, al3, ah3, al3, qnh, qnl, 1, 1]   (half 0 = k0-7, half 1 = k8-15)
//  B (ref)  : [bh3, bh3, bl3, bl3, 1, 1, rnh, rnl]
//  sum_k A_k B_k = (ah+al)·(bh+bl) + qn + rn = ||q-r||^2 (exact to ~fp32)
__device__ __forceinline__ f16x8 make_afrag(float x, float y, float z, int half) {
    const float rn = fmaf(x, x, fmaf(y, y, z * z));
    const float ax = -2.f * x, ay = -2.f * y, az = -2.f * z;
    const _Float16 ahx = (_Float16)ax, ahy = (_Float16)ay, ahz = (_Float16)az;
    const _Float16 alx = (_Float16)(ax - (float)ahx);
    const _Float16 aly = (_Float16)(ay - (float)ahy);
    const _Float16 alz = (_Float16)(az - (float)ahz);
    const _Float16 rh = (_Float16)rn, rl = (_Float16)(rn - (float)rh);
    const _Float16 one = (_Float16)1.f;
    if (half == 0) return (f16x8){ahx, ahy, ahz, alx, aly, alz, ahx, ahy};
    return (f16x8){ahz, alx, aly, alz, rh, rl, one, one};
}
__device__ __forceinline__ void make_bfrags(float x, float y, float z,
                                            f16x8* b0, f16x8* b1) {
    const float rn = fmaf(x, x, fmaf(y, y, z * z));
    const _Float16 bhx = (_Float16)x, bhy = (_Float16)y, bhz = (_Float16)z;
    const _Float16 blx = (_Float16)(x - (float)bhx);
    const _Float16 bly = (_Float16)(y - (float)bhy);
    const _Float16 blz = (_Float16)(z - (float)bhz);
    const _Float16 rh = (_Float16)rn, rl = (_Float16)(rn - (float)rh);
    const _Float16 one = (_Float16)1.f;
    *b0 = (f16x8){bhx, bhy, bhz, bhx, bhy, bhz, blx, bly};
    *b1 = (f16x8){blz, blx, bly, blz, one, one, rh, rl};
}

// Stage 1 (fused pack): 32x32x16 MFMA distance tiles, running column-min.
// Per wave: 64 queries (2 A-frags built in-lane). Ref chunk packed during LDS
// staging. tp loop is unroll-1 with 1-step register prefetch (bounded VGPRs).
__global__ __launch_bounds__(256) void nn_mfma(
    const float* __restrict__ preds, const float* __restrict__ gts,
    int M, int N, int B, int rsplit, int Qstride, float* __restrict__ part)
{
    const int zc    = blockIdx.z;
    const int dir   = zc / rsplit;       // 0: q=preds ref=gts ; 1: q=gts ref=preds
    const int chunk = zc - dir * rsplit;
    const int b     = blockIdx.y;

    const int Q = dir ? N : M;
    const int R = dir ? M : N;
    const float* __restrict__ qraw = (dir ? gts : preds) + (size_t)b * Q * 3;
    const float* __restrict__ rraw = (dir ? preds : gts) + (size_t)b * R * 3;

    const int q0blk = blockIdx.x * 256;
    if (q0blk >= Q) return;
    const int tid  = threadIdx.x;
    const int lane = tid & 63, w = tid >> 6;
    const int q0   = q0blk + w * 64;            // wave owns queries q0..q0+63
    const int lrow = lane & 31, lh = lane >> 5; // A row / k-half

    float ax = 0.f, ay = 0.f, az = 0.f, bx = 0.f, by = 0.f, bz = 0.f;
    const int qa = q0 + lrow, qb = q0 + 32 + lrow;
    if (qa < Q) { const float* s = qraw + (size_t)qa * 3; ax = s[0]; ay = s[1]; az = s[2]; }
    if (qb < Q) { const float* s = qraw + (size_t)qb * 3; bx = s[0]; by = s[1]; bz = s[2]; }
    const f16x8 af0 = make_afrag(ax, ay, az, lh);
    const f16x8 af1 = make_afrag(bx, by, bz, lh);

    __shared__ f16x8 sB[TILE * 2];

    const f32x16 z16 = {0.f,0.f,0.f,0.f, 0.f,0.f,0.f,0.f,
                        0.f,0.f,0.f,0.f, 0.f,0.f,0.f,0.f};
    f32x16 rm0, rm1;
    #pragma unroll
    for (int j = 0; j < 16; ++j) { rm0[j] = INFINITY; rm1[j] = INFINITY; }

    const int tilesTotal = (R + TILE - 1) / TILE;
    const int tpc = (tilesTotal + rsplit - 1) / rsplit;
    const int t0 = chunk * tpc;
    const int t1 = min(tilesTotal, t0 + tpc);

    for (int tt = t0; tt < t1; ++tt) {
        const int s0 = tt * TILE;
        __syncthreads();
        #pragma unroll
        for (int k = 0; k < 2; ++k) {
            const int p  = tid + k * 256;
            const int gi = s0 + p;
            f16x8 b0, b1;
            if (gi < R) {
                const float* s = rraw + (size_t)gi * 3;
                make_bfrags(s[0], s[1], s[2], &b0, &b1);
            } else {
                const _Float16 z0 = (_Float16)0.f, one = (_Float16)1.f;
                const _Float16 inf16 = (_Float16)__builtin_huge_valf();
                b0 = (f16x8){z0, z0, z0, z0, z0, z0, z0, z0};
                b1 = (f16x8){z0, z0, z0, z0, one, one, inf16, z0};  // pad -> +inf
            }
            sB[p * 2]     = b0;
            sB[p * 2 + 1] = b1;
        }
        __syncthreads();

        const char* sbase = (const char*)sB + lrow * 32 + lh * 16;
        f16x8 nb0 = *(const f16x8*)(sbase);
        f16x8 nb1 = *(const f16x8*)(sbase + 1024);
        #pragma unroll 1
        for (int tp = 0; tp < 8; ++tp) {
            const f16x8 cb0 = nb0, cb1 = nb1;
            if (tp < 7) {   // uniform branch: prefetch next 64-ref pair
                nb0 = *(const f16x8*)(sbase + (2 * tp + 2) * 1024);
                nb1 = *(const f16x8*)(sbase + (2 * tp + 3) * 1024);
            }
            const f32x16 dA0 = __builtin_amdgcn_mfma_f32_32x32x16_f16(af0, cb0, z16, 0, 0, 0);
            const f32x16 dA1 = __builtin_amdgcn_mfma_f32_32x32x16_f16(af0, cb1, z16, 0, 0, 0);
            const f32x16 dB0 = __builtin_amdgcn_mfma_f32_32x32x16_f16(af1, cb0, z16, 0, 0, 0);
            const f32x16 dB1 = __builtin_amdgcn_mfma_f32_32x32x16_f16(af1, cb1, z16, 0, 0, 0);
            #pragma unroll
            for (int j = 0; j < 16; ++j) rm0[j] = min3f(dA0[j], dA1[j], rm0[j]);
            #pragma unroll
            for (int j = 0; j < 16; ++j) rm1[j] = min3f(dB0[j], dB1[j], rm1[j]);
        }
    }

    // reduce over the 32 ref-columns (xor bits 0-4 stay within the lh group)
    #pragma unroll
    for (int m2 = 1; m2 <= 16; m2 <<= 1) {
        #pragma unroll
        for (int j = 0; j < 16; ++j) {
            rm0[j] = fminf(rm0[j], __shfl_xor(rm0[j], m2, 64));
            rm1[j] = fminf(rm1[j], __shfl_xor(rm1[j], m2, 64));
        }
    }

    // lanes 0 and 32 hold complementary row sets: row = (j&3)+8*(j>>2)+4*lh
    if ((lane & 31) == 0) {
        const size_t pbase = (((size_t)dir * B + b) * rsplit + chunk) * (size_t)Qstride + q0;
        #pragma unroll
        for (int j = 0; j < 16; ++j) {
            const int row = (j & 3) + 8 * (j >> 2) + 4 * lh;
            part[pbase + row]      = rm0[j];
            part[pbase + 32 + row] = rm1[j];
        }
    }
}

// Stage 2: combine rsplit partial mins, Huber, wave reduce, atomicAdd.
__global__ __launch_bounds__(256) void huber_reduce(
    const float* __restrict__ part, const int* __restrict__ cptr,
    int M, int N, int B, int rsplit, int Qstride, float* __restrict__ out)
{
    const int dir = blockIdx.z;
    const int b   = blockIdx.y;
    const int Q   = dir ? N : M;
    const int j   = blockIdx.x * blockDim.x + threadIdx.x;

    float h = 0.f;
    if (j < Q) {
        const size_t base = (((size_t)dir * B + b) * rsplit) * (size_t)Qstride + j;
        float v = part[base];
        #pragma unroll 4
        for (int k = 1; k < rsplit; ++k) v = fminf(v, part[base + (size_t)k * Qstride]);
        const float c = decode_scalar(cptr);
        h = (v < c) ? (0.5f * v * v) : fmaf(c, v, -0.5f * c * c);
    }

    #pragma unroll
    for (int off = 32; off > 0; off >>= 1) h += __shfl_down(h, off, 64);
    if ((threadIdx.x & 63) == 0) atomicAdd(out, h);
}

extern "C" void kernel_launch(void* const* d_in, const int* in_sizes, int n_in,
                              void* d_out, int out_size, void* d_ws, size_t ws_size,
                              hipStream_t stream) {
    const float* preds = (const float*)d_in[0];
    const float* gts   = (const float*)d_in[1];
    const int*   cptr  = (const int*)d_in[2];

    const int B = 4, D = 3;
    const int M = in_sizes[0] / (B * D);
    const int N = in_sizes[1] / (B * D);
    const int Qmax = (M > N) ? M : N;
    const int Qstride = (Qmax + 255) & ~255;
    const int rsplit = 4;

    float* part = (float*)d_ws;   // 2*B*rsplit*Qstride floats (1 MB @ 8192)
    hipMemsetAsync(d_out, 0, (size_t)out_size * sizeof(float), stream);

    dim3 g1(Qstride / 256, B, 2 * rsplit);
    nn_mfma<<<g1, 256, 0, stream>>>(preds, gts, M, N, B, rsplit, Qstride, part);

    dim3 g2((Qmax + 255) / 256, B, 2);
    huber_reduce<<<g2, 256, 0, stream>>>(part, cptr, M, N, B, rsplit, Qstride,
                                         (float*)d_out);
}

// Round 9
// 58.057 us; speedup vs baseline: 1.2491x; 1.0111x over previous
//
#include <hip/hip_runtime.h>
#include <math.h>

typedef _Float16 f16x8 __attribute__((ext_vector_type(8)));
typedef float f32x16 __attribute__((ext_vector_type(16)));

#define TILE 1024  // refs per LDS stage: 1024 * 32B = 32 KB

__device__ __forceinline__ float decode_scalar(const int* p) {
    int i = *p;
    if (i > -16777216 && i < 16777216) return (float)i;
    return __int_as_float(i);
}

// K=16 encoding, a = -2*pt, hi/lo f16 split, rn = |pt|^2:
//  A (query): [ah3, al3, ah3, al3, qnh, qnl, 1, 1]   (half 0 = k0-7, half 1 = k8-15)
//  B (ref)  : [bh3, bh3, bl3, bl3, 1, 1, rnh, rnl]
//  sum_k A_k B_k = (ah+al)·(bh+bl) + qn + rn = ||q-r||^2 (exact to ~fp32)
__device__ __forceinline__ f16x8 make_afrag(float x, float y, float z, int half) {
    const float rn = fmaf(x, x, fmaf(y, y, z * z));
    const float ax = -2.f * x, ay = -2.f * y, az = -2.f * z;
    const _Float16 ahx = (_Float16)ax, ahy = (_Float16)ay, ahz = (_Float16)az;
    const _Float16 alx = (_Float16)(ax - (float)ahx);
    const _Float16 aly = (_Float16)(ay - (float)ahy);
    const _Float16 alz = (_Float16)(az - (float)ahz);
    const _Float16 rh = (_Float16)rn, rl = (_Float16)(rn - (float)rh);
    const _Float16 one = (_Float16)1.f;
    if (half == 0) return (f16x8){ahx, ahy, ahz, alx, aly, alz, ahx, ahy};
    return (f16x8){ahz, alx, aly, alz, rh, rl, one, one};
}
__device__ __forceinline__ void make_bfrags(float x, float y, float z,
                                            f16x8* b0, f16x8* b1) {
    const float rn = fmaf(x, x, fmaf(y, y, z * z));
    const _Float16 bhx = (_Float16)x, bhy = (_Float16)y, bhz = (_Float16)z;
    const _Float16 blx = (_Float16)(x - (float)bhx);
    const _Float16 bly = (_Float16)(y - (float)bhy);
    const _Float16 blz = (_Float16)(z - (float)bhz);
    const _Float16 rh = (_Float16)rn, rl = (_Float16)(rn - (float)rh);
    const _Float16 one = (_Float16)1.f;
    *b0 = (f16x8){bhx, bhy, bhz, bhx, bhy, bhz, blx, bly};
    *b1 = (f16x8){blz, blx, bly, blz, one, one, rh, rl};
}

// Stage 1 (fused pack): 32x32x16 MFMA distance tiles, running column-min.
// Queries = A (2 frags/wave, built in-lane), refs = B (packed during LDS stage).
__global__ __launch_bounds__(256) void nn_mfma(
    const float* __restrict__ preds, const float* __restrict__ gts,
    int M, int N, int B, int rsplit, int Qstride, float* __restrict__ part)
{
    const int zc    = blockIdx.z;
    const int dir   = zc / rsplit;       // 0: q=preds ref=gts ; 1: q=gts ref=preds
    const int chunk = zc - dir * rsplit;
    const int b     = blockIdx.y;

    const int Q = dir ? N : M;
    const int R = dir ? M : N;
    const float* __restrict__ qraw = (dir ? gts : preds) + (size_t)b * Q * 3;
    const float* __restrict__ rraw = (dir ? preds : gts) + (size_t)b * R * 3;

    const int q0blk = blockIdx.x * 256;
    if (q0blk >= Q) return;
    const int tid  = threadIdx.x;
    const int lane = tid & 63, w = tid >> 6;
    const int q0   = q0blk + w * 64;            // wave owns queries q0..q0+63
    const int lrow = lane & 31, lh = lane >> 5; // A row / k-half

    float ax = 0.f, ay = 0.f, az = 0.f, bx = 0.f, by = 0.f, bz = 0.f;
    const int qa = q0 + lrow, qb = q0 + 32 + lrow;
    if (qa < Q) { const float* s = qraw + (size_t)qa * 3; ax = s[0]; ay = s[1]; az = s[2]; }
    if (qb < Q) { const float* s = qraw + (size_t)qb * 3; bx = s[0]; by = s[1]; bz = s[2]; }
    const f16x8 af0 = make_afrag(ax, ay, az, lh);
    const f16x8 af1 = make_afrag(bx, by, bz, lh);

    __shared__ f16x8 sB[TILE * 2];

    const f32x16 z16 = {0.f,0.f,0.f,0.f, 0.f,0.f,0.f,0.f,
                        0.f,0.f,0.f,0.f, 0.f,0.f,0.f,0.f};
    f32x16 rm0, rm1;
    #pragma unroll
    for (int j = 0; j < 16; ++j) { rm0[j] = INFINITY; rm1[j] = INFINITY; }

    const int tilesTotal = (R + TILE - 1) / TILE;
    const int tpc = (tilesTotal + rsplit - 1) / rsplit;
    const int t0 = chunk * tpc;
    const int t1 = min(tilesTotal, t0 + tpc);

    for (int tt = t0; tt < t1; ++tt) {
        const int s0 = tt * TILE;
        __syncthreads();
        #pragma unroll
        for (int k = 0; k < 4; ++k) {
            const int p  = tid + k * 256;
            const int gi = s0 + p;
            f16x8 b0, b1;
            if (gi < R) {
                const float* s = rraw + (size_t)gi * 3;
                make_bfrags(s[0], s[1], s[2], &b0, &b1);
            } else {
                const _Float16 z0 = (_Float16)0.f, one = (_Float16)1.f;
                const _Float16 big = (_Float16)60000.f;   // pad -> huge dist (finite)
                b0 = (f16x8){z0, z0, z0, z0, z0, z0, z0, z0};
                b1 = (f16x8){z0, z0, z0, z0, one, one, big, z0};
            }
            sB[p * 2]     = b0;
            sB[p * 2 + 1] = b1;
        }
        __syncthreads();

        // lane reads ref col (32*t + lrow), k-half lh: addr = t*1024B + lrow*32 + lh*16
        const char* sbase = (const char*)sB + lrow * 32 + lh * 16;
        f16x8 nb0 = *(const f16x8*)(sbase);
        f16x8 nb1 = *(const f16x8*)(sbase + 1024);
        #pragma unroll 1
        for (int tp = 0; tp < TILE / 64; ++tp) {
            const f16x8 cb0 = nb0, cb1 = nb1;
            if (tp < TILE / 64 - 1) {   // uniform branch: prefetch next 64-ref pair
                nb0 = *(const f16x8*)(sbase + (2 * tp + 2) * 1024);
                nb1 = *(const f16x8*)(sbase + (2 * tp + 3) * 1024);
            }
            const f32x16 d00 = __builtin_amdgcn_mfma_f32_32x32x16_f16(af0, cb0, z16, 0, 0, 0);
            const f32x16 d01 = __builtin_amdgcn_mfma_f32_32x32x16_f16(af0, cb1, z16, 0, 0, 0);
            #pragma unroll
            for (int j = 0; j < 16; ++j)
                rm0[j] = fminf(rm0[j], fminf(d00[j], d01[j]));
            const f32x16 d10 = __builtin_amdgcn_mfma_f32_32x32x16_f16(af1, cb0, z16, 0, 0, 0);
            const f32x16 d11 = __builtin_amdgcn_mfma_f32_32x32x16_f16(af1, cb1, z16, 0, 0, 0);
            #pragma unroll
            for (int j = 0; j < 16; ++j)
                rm1[j] = fminf(rm1[j], fminf(d10[j], d11[j]));
        }
    }

    // reduce over the 32 ref-columns (xor bits 0-4 stay within the lh group)
    #pragma unroll
    for (int m2 = 1; m2 <= 16; m2 <<= 1) {
        #pragma unroll
        for (int j = 0; j < 16; ++j) {
            rm0[j] = fminf(rm0[j], __shfl_xor(rm0[j], m2, 64));
            rm1[j] = fminf(rm1[j], __shfl_xor(rm1[j], m2, 64));
        }
    }

    // lanes 0 and 32 hold complementary row sets: row = (j&3)+8*(j>>2)+4*lh
    if ((lane & 31) == 0) {
        const size_t pbase = (((size_t)dir * B + b) * rsplit + chunk) * (size_t)Qstride + q0;
        #pragma unroll
        for (int j = 0; j < 16; ++j) {
            const int row = (j & 3) + 8 * (j >> 2) + 4 * lh;
            part[pbase + row]      = rm0[j];
            part[pbase + 32 + row] = rm1[j];
        }
    }
}

// Stage 2: combine rsplit partial mins, Huber, wave reduce, atomicAdd.
__global__ __launch_bounds__(256) void huber_reduce(
    const float* __restrict__ part, const int* __restrict__ cptr,
    int M, int N, int B, int rsplit, int Qstride, float* __restrict__ out)
{
    const int dir = blockIdx.z;
    const int b   = blockIdx.y;
    const int Q   = dir ? N : M;
    const int j   = blockIdx.x * blockDim.x + threadIdx.x;

    float h = 0.f;
    if (j < Q) {
        const size_t base = (((size_t)dir * B + b) * rsplit) * (size_t)Qstride + j;
        float v = part[base];
        #pragma unroll 8
        for (int k = 1; k < rsplit; ++k) v = fminf(v, part[base + (size_t)k * Qstride]);
        const float c = decode_scalar(cptr);
        h = (v < c) ? (0.5f * v * v) : fmaf(c, v, -0.5f * c * c);
    }

    #pragma unroll
    for (int off = 32; off > 0; off >>= 1) h += __shfl_down(h, off, 64);
    if ((threadIdx.x & 63) == 0) atomicAdd(out, h);
}

extern "C" void kernel_launch(void* const* d_in, const int* in_sizes, int n_in,
                              void* d_out, int out_size, void* d_ws, size_t ws_size,
                              hipStream_t stream) {
    const float* preds = (const float*)d_in[0];
    const float* gts   = (const float*)d_in[1];
    const int*   cptr  = (const int*)d_in[2];

    const int B = 4, D = 3;
    const int M = in_sizes[0] / (B * D);
    const int N = in_sizes[1] / (B * D);
    const int Qmax = (M > N) ? M : N;
    const int Qstride = (Qmax + 255) & ~255;
    const int rsplit = 8;

    float* part = (float*)d_ws;   // 2*B*rsplit*Qstride floats (2 MB @ 8192)
    hipMemsetAsync(d_out, 0, (size_t)out_size * sizeof(float), stream);

    dim3 g1(Qstride / 256, B, 2 * rsplit);
    nn_mfma<<<g1, 256, 0, stream>>>(preds, gts, M, N, B, rsplit, Qstride, part);

    dim3 g2((Qmax + 255) / 256, B, 2);
    huber_reduce<<<g2, 256, 0, stream>>>(part, cptr, M, N, B, rsplit, Qstride,
                                         (float*)d_out);
}